// Round 5
// baseline (33.492 us; speedup 1.0000x reference)
//
#include <hip/hip_runtime.h>
#include <math.h>

#define BATCH 128
#define NPRE  1024
#define NPOST 256
#define NCH   16     // k-chunks per neuron (1 wave per chunk)
#define CLEN  64     // NPRE / NCH
#define NJ    64     // neurons per block (NPOST/4)
#define CH    8      // weight prefetch batch

__device__ __forceinline__ float rlf(float v, int lane) {
    // wave-uniform lane -> v_readlane_b32 (no LDS traffic)
    return __int_as_float(__builtin_amdgcn_readlane(__float_as_int(v), lane));
}

__device__ __forceinline__ float lambertw0_f(float z) {
    // Principal branch for z in [-1/e, 0); mirrors reference (clip + init + 12 Halley)
    const float INV_E = 0.36787944117144233f;
    float zc = fminf(fmaxf(z, -INV_E + 1e-8f), -1e-30f);
    float w;
    if (zc < -0.2f) {
        w = -1.0f + sqrtf(2.0f * (1.0f + 2.718281828459045f * zc));
    } else {
        w = zc * (1.0f - zc);
    }
#pragma unroll
    for (int it = 0; it < 12; ++it) {
        float ew  = expf(w);
        float f   = w * ew - zc;
        float wp1 = w + 1.0f;
        w = w - f / (ew * wp1 - (w + 2.0f) * f / (2.0f * wp1));
    }
    return w;
}

__device__ __forceinline__ unsigned long long shflxor64(unsigned long long v, int s) {
    unsigned lo = (unsigned)v, hi = (unsigned)(v >> 32);
    lo = __shfl_xor(lo, s);
    hi = __shfl_xor(hi, s);
    return (((unsigned long long)hi) << 32) | lo;
}

__global__ __launch_bounds__(1024, 8)
void ttfs_kernel(const float* __restrict__ spikes,   // (BATCH, NPRE)
                 const float* __restrict__ Wt,       // (NPRE, NPOST)
                 float* __restrict__ out)            // (BATCH, NPOST)
{
    __shared__ unsigned long long sbuf[2][NPRE];     // double-buffered sort exchange
    __shared__ float4 tab[NPRE + 1];                 // (s, e^s, s*e^s, 0) sorted, +inf pad
    __shared__ int    sidx[NPRE + 4];                // sorted original indices
    __shared__ float  cA[NCH][NJ], cB[NCH][NJ];      // chunk sums
    __shared__ int    ffk[NCH][NJ];                  // chunk-found k (-1 none)
    __shared__ float  ffA[NCH][NJ], ffB[NCH][NJ];

    const int tid = threadIdx.x;
    const int b   = (int)blockIdx.x >> 2;
    const int h   = (int)blockIdx.x & 3;

    // ---- load + pack (key asc, idx asc) == u64 asc for positive floats ----
    {
        float s = spikes[b * NPRE + tid];
        unsigned long long v =
            (((unsigned long long)__float_as_uint(s)) << 32) | (unsigned)tid;

        // ---- hybrid bitonic sort: shfl for stride<=32, dbuf-LDS for >=64 ----
        int p = 0;
        for (int size = 2; size <= NPRE; size <<= 1) {
            int stride = size >> 1;
            for (; stride >= 64; stride >>= 1) {
                sbuf[p][tid] = v;
                __syncthreads();
                unsigned long long q = sbuf[p][tid ^ stride];
                p ^= 1;   // next LDS phase writes the other buffer: no 2nd barrier
                bool keepmin = (((tid & stride) == 0) == ((tid & size) == 0));
                v = ((q < v) == keepmin) ? q : v;
            }
            for (stride = (stride > 32 ? 32 : stride); stride >= 1; stride >>= 1) {
                unsigned long long q = shflxor64(v, stride);
                bool keepmin = (((tid & stride) == 0) == ((tid & size) == 0));
                v = ((q < v) == keepmin) ? q : v;
            }
        }

        float sv = __uint_as_float((unsigned)(v >> 32));
        float e  = expf(sv);
        tab[tid]  = make_float4(sv, e, sv * e, 0.0f);
        sidx[tid] = (int)(unsigned)(v & 0xffffffffULL);
    }
    if (tid == 0) {
        tab[NPRE]  = make_float4(INFINITY, INFINITY, 0.0f, 0.0f);
        sidx[NPRE] = 0; sidx[NPRE + 1] = 0; sidx[NPRE + 2] = 0; sidx[NPRE + 3] = 0;
    }
    __syncthreads();

    // ---- chunked scan: one wave per chunk, 64 neurons per lane-set ----
    const int c  = tid >> 6;         // 0..15 (wave-uniform)
    const int jj = tid & (NJ - 1);   // 0..63 (== lane)
    const int j0 = h * NJ;
    const float* __restrict__ Wcol = Wt + j0 + jj;
    const int k0 = c * CLEN;
    const int4* __restrict__ sidx4 = (const int4*)sidx;

    // per-lane distributed table: lane L holds entry k0+L
    const int L = tid & 63;
    const float4 tA4  = tab[k0 + L];
    const float4 tEnd = tab[k0 + CLEN];   // chunk boundary (last chunk: +inf pad)

#define LOADW(kb, dst)                                                        \
    {                                                                         \
        _Pragma("unroll")                                                     \
        for (int q = 0; q < CH / 4; ++q) {                                    \
            int4 I = sidx4[(k0 + (kb)) / 4 + q];                              \
            dst[4 * q + 0] = Wcol[I.x * NPOST];                               \
            dst[4 * q + 1] = Wcol[I.y * NPOST];                               \
            dst[4 * q + 2] = Wcol[I.z * NPOST];                               \
            dst[4 * q + 3] = Wcol[I.w * NPOST];                               \
        }                                                                     \
    }

    // pass 1: chunk-local sums (last chunk's sums never used as offsets)
    float A = 0.0f, Bq = 0.0f;
    if (c < NCH - 1) {
        float wv[CH];
        LOADW(0, wv);
        for (int kb = 0; kb < CLEN; kb += CH) {
            float wn[CH];
            const int nb = kb + CH;
            if (nb < CLEN) LOADW(nb, wn);
#pragma unroll
            for (int i = 0; i < CH; ++i) {
                const int Lr = kb + i;
                A  = fmaf(wv[i], rlf(tA4.y, Lr), A);
                Bq = fmaf(wv[i], rlf(tA4.z, Lr), Bq);
            }
            if (nb < CLEN) {
#pragma unroll
                for (int i = 0; i < CH; ++i) wv[i] = wn[i];
            }
        }
    }
    cA[c][jj] = A; cB[c][jj] = Bq;
    __syncthreads();

    // pass 2: exclusive prefix over chunks
    float offA = 0.0f, offB = 0.0f;
    for (int cc = 0; cc < c; ++cc) { offA += cA[cc][jj]; offB += cB[cc][jj]; }

    // pass 3: delayed-gate scan. Gate at iteration kk tests window k0+kk-1:
    //   V(s_{k}) >= 1  <=>  A_{<k}*s_k - B_{<k} >= e^{s_k}
    A = offA; Bq = offB;
    int   fk = -1; float fA = 0.0f, fB = 0.0f;
    bool  done = false;
    if (c > 0) {
        // pre-gate: membrane already crossed before k0 -> earlier chunk owns it.
        // 1e-5 relative margin so cross-chunk ulp reordering can never flip this.
        float s0 = rlf(tA4.x, 0), e0 = rlf(tA4.y, 0);
        done = fmaf(offA, s0, -offB) >= e0 * 1.00001f;
    }
    if (!__all(done)) {
        float wv[CH];
        LOADW(0, wv);
        for (int kb = 0; kb < CLEN; kb += CH) {
            float wn[CH];
            const int nb = kb + CH;
            if (nb < CLEN) LOADW(nb, wn);
#pragma unroll
            for (int i = 0; i < CH; ++i) {
                const int kk = kb + i;
                float sk  = rlf(tA4.x, kk);
                float ek  = rlf(tA4.y, kk);
                float sek = rlf(tA4.z, kk);
                if (!done && kk > 0) {
                    float gate = fmaf(A, sk, -Bq);
                    if (gate >= ek) { fA = A; fB = Bq; fk = k0 + kk - 1; done = true; }
                }
                A  = fmaf(wv[i], ek,  A);
                Bq = fmaf(wv[i], sek, Bq);
            }
            if (__all(done)) break;
            if (nb < CLEN) {
#pragma unroll
                for (int i = 0; i < CH; ++i) wv[i] = wn[i];
            }
        }
        if (!done) {
            // tail gate: window k0+CLEN-1 against chunk boundary (or +inf pad)
            float gate = fmaf(A, tEnd.x, -Bq);
            if (gate >= tEnd.y) { fA = A; fB = Bq; fk = k0 + CLEN - 1; }
        }
    }
    ffk[c][jj] = fk; ffA[c][jj] = fA; ffB[c][jj] = fB;
    __syncthreads();

    // ---- resolve: one thread per neuron picks earliest chunk, Lambert W once ----
    if (tid < NJ) {
        const int jr = tid;
        int fk2 = -1; float fA2 = 0.0f, fB2 = 0.0f;
#pragma unroll
        for (int cc = 0; cc < NCH; ++cc) {
            int k = ffk[cc][jr];
            if (fk2 < 0 && k >= 0) { fk2 = k; fA2 = ffA[cc][jr]; fB2 = ffB[cc][jr]; }
        }
        float result = INFINITY;
        const float INV_E = 0.36787944117144233f;
        const float* __restrict__ Wc2 = Wt + j0 + jr;
        if (fk2 >= 0) {
            float r  = fB2 / fA2;
            float ez = expf(fminf(fmaxf(r, -30.0f), 30.0f));
            float z  = -ez / fA2;
            bool valid = (fA2 > 0.0f) && (z >= -INV_E);
            float t = r - lambertw0_f(z);
            bool ok = valid && (t >= tab[fk2].x) && (fk2 == NPRE - 1 || t <= tab[fk2 + 1].x);
            if (ok) {
                result = t;
            } else {
                // rare fp-edge fallback: faithful sequential scan from fk2+1
                float A2 = fA2, B2 = fB2;
                for (int k = fk2 + 1; k < NPRE; ++k) {
                    float w = Wc2[sidx[k] * NPOST];
                    float4 t3 = tab[k];
                    A2 = fmaf(w, t3.y, A2);
                    B2 = fmaf(w, t3.z, B2);
                    if (A2 <= 0.0f) continue;
                    float r2  = B2 / A2;
                    float ez2 = expf(fminf(fmaxf(r2, -30.0f), 30.0f));
                    float z2  = -ez2 / A2;
                    if (z2 < -INV_E) continue;
                    float t2 = r2 - lambertw0_f(z2);
                    if (t2 < t3.x) continue;
                    if (k < NPRE - 1 && t2 > tab[k + 1].x) continue;
                    result = t2;
                    break;
                }
            }
        }
        out[b * NPOST + j0 + jr] = result;
    }
}

extern "C" void kernel_launch(void* const* d_in, const int* in_sizes, int n_in,
                              void* d_out, int out_size, void* d_ws, size_t ws_size,
                              hipStream_t stream) {
    const float* spikes  = (const float*)d_in[0];   // (128, 1024) f32
    const float* weights = (const float*)d_in[1];   // (1024, 256) f32
    float* outp = (float*)d_out;                    // (128, 256) f32
    ttfs_kernel<<<dim3(BATCH * 4), dim3(1024), 0, stream>>>(spikes, weights, outp);
}